// Round 5
// baseline (253.057 us; speedup 1.0000x reference)
//
#include <hip/hip_runtime.h>
#include <hip/hip_bf16.h>
#include <math.h>

#define N_NODES 10000
#define D 128
#define NCOPY 8

typedef unsigned int uint_t;
typedef unsigned short ushort_t;

// float -> bf16 bits, round-nearest-even (finite inputs only)
__device__ inline uint_t f2bf_bits(float f) {
    uint_t u = __float_as_uint(f);
    return (u + 0x7fffu + ((u >> 16) & 1u)) >> 16;
}
__device__ inline uint_t pack_bf2(float lo, float hi) {
    return (f2bf_bits(hi) << 16) | f2bf_bits(lo);
}

// ---------------- tiny zero fill ----------------
__global__ void zero_kernel(uint4* __restrict__ p, int n16) {
    int i = blockIdx.x * blockDim.x + threadIdx.x;
    if (i < n16) p[i] = make_uint4(0u, 0u, 0u, 0u);
}

// ---------------- CSR build ----------------
// pass 1: 8-way replicated histogram + per-edge rank within copy
__global__ void rank_kernel(const int* __restrict__ dst, int E,
                            int* __restrict__ deg8, int* __restrict__ pos) {
    int i = blockIdx.x * blockDim.x + threadIdx.x;
    if (i < E) {
        int c = blockIdx.x & (NCOPY - 1);
        pos[i] = atomicAdd(&deg8[c * N_NODES + dst[i]], 1);
    }
}

// single-block scan over summed copies -> offsets[0..n] and per-copy bases
#define SCAN_PER 10
__global__ __launch_bounds__(1024) void scan_kernel(const int* __restrict__ deg8,
                                                    int* __restrict__ offsets,
                                                    int* __restrict__ base8, int n) {
    __shared__ int wsum[16];
    __shared__ int wpre[16];
    int tid = threadIdx.x;
    int lane = tid & 63, wid = tid >> 6;
    int base = tid * SCAN_PER;
    int loc[SCAN_PER];
    int s = 0;
#pragma unroll
    for (int q = 0; q < SCAN_PER; ++q) {
        int idx = base + q;
        int tot = 0;
        if (idx < n) {
#pragma unroll
            for (int c = 0; c < NCOPY; ++c) tot += deg8[c * N_NODES + idx];
        }
        s += tot;
        loc[q] = s;  // inclusive within thread
    }
    int mysum = s;
#pragma unroll
    for (int off = 1; off < 64; off <<= 1) {
        int t = __shfl_up(s, off, 64);
        if (lane >= off) s += t;
    }
    if (lane == 63) wsum[wid] = s;
    __syncthreads();
    if (wid == 0 && lane < 16) {
        int v = wsum[lane];
        int ss = v;
#pragma unroll
        for (int off = 1; off < 16; off <<= 1) {
            int t = __shfl_up(ss, off, 16);
            if ((lane & 15) >= off) ss += t;
        }
        wpre[lane] = ss - v;
    }
    __syncthreads();
    int thread_excl = wpre[wid] + (s - mysum);
#pragma unroll
    for (int q = 0; q < SCAN_PER; ++q) {
        int idx = base + q;
        if (idx < n) {
            offsets[idx + 1] = thread_excl + loc[q];
            int run = thread_excl + (q ? loc[q - 1] : 0);  // exclusive start of node idx
#pragma unroll
            for (int c = 0; c < NCOPY; ++c) {
                base8[c * N_NODES + idx] = run;
                run += deg8[c * N_NODES + idx];
            }
        }
    }
    if (tid == 0) offsets[0] = 0;
}

// pass 2: pure streaming write, no atomics
__global__ void csr_write_kernel(const int* __restrict__ src, const int* __restrict__ dst,
                                 const int* __restrict__ pos, int E,
                                 const int* __restrict__ base8, int* __restrict__ csr_src) {
    int i = blockIdx.x * blockDim.x + threadIdx.x;
    if (i < E) {
        int c = (i >> 8) & (NCOPY - 1);  // same copy mapping as rank_kernel (256 thr/block)
        csr_src[base8[c * N_NODES + dst[i]] + pos[i]] = src[i];
    }
}

// ---------------- fp32 -> bf16 mirror ----------------
__global__ void f2bf_kernel(const float* __restrict__ in, ushort_t* __restrict__ out, int n8) {
    int i = blockIdx.x * blockDim.x + threadIdx.x;
    if (i >= n8) return;
    const float4* p = (const float4*)in + (size_t)i * 2;
    float4 a = p[0], b = p[1];
    uint4 o;
    o.x = pack_bf2(a.x, a.y);
    o.y = pack_bf2(a.z, a.w);
    o.z = pack_bf2(b.x, b.y);
    o.w = pack_bf2(b.z, b.w);
    ((uint4*)out)[i] = o;
}

// ---------------- aggregation (segment mean, bf16 gather) ----------------
// 128 threads per node: 8 edge-groups x 16 lanes; each lane covers 8 features (16B)
__global__ __launch_bounds__(128) void aggregate_kernel(const ushort_t* __restrict__ h16,
                                                        const int* __restrict__ offsets,
                                                        const int* __restrict__ csr_src,
                                                        float* __restrict__ mean) {
    __shared__ float tmp[16][8];
    int node = blockIdx.x;
    int tid = threadIdx.x;
    int g = tid >> 4;          // 0..7
    int fl = (tid & 15) * 8;   // feature base
    int beg = offsets[node], end = offsets[node + 1];
    float4 aA = make_float4(0.f, 0.f, 0.f, 0.f);
    float4 aB = make_float4(0.f, 0.f, 0.f, 0.f);
    for (int e = beg + g; e < end; e += 8) {
        int s = csr_src[e];
        uint4 v = *(const uint4*)&h16[s * D + fl];
        aA.x += __uint_as_float(v.x << 16);
        aA.y += __uint_as_float(v.x & 0xffff0000u);
        aA.z += __uint_as_float(v.y << 16);
        aA.w += __uint_as_float(v.y & 0xffff0000u);
        aB.x += __uint_as_float(v.z << 16);
        aB.y += __uint_as_float(v.z & 0xffff0000u);
        aB.z += __uint_as_float(v.w << 16);
        aB.w += __uint_as_float(v.w & 0xffff0000u);
    }
#pragma unroll
    for (int off = 16; off <= 32; off <<= 1) {
        aA.x += __shfl_xor(aA.x, off, 64);
        aA.y += __shfl_xor(aA.y, off, 64);
        aA.z += __shfl_xor(aA.z, off, 64);
        aA.w += __shfl_xor(aA.w, off, 64);
        aB.x += __shfl_xor(aB.x, off, 64);
        aB.y += __shfl_xor(aB.y, off, 64);
        aB.z += __shfl_xor(aB.z, off, 64);
        aB.w += __shfl_xor(aB.w, off, 64);
    }
    if (tid >= 64 && (tid & 63) < 16) {
        int l = tid & 15;
        *(float4*)&tmp[l][0] = aA;
        *(float4*)&tmp[l][4] = aB;
    }
    __syncthreads();
    if (tid < 16) {
        float4 oA = *(const float4*)&tmp[tid][0];
        float4 oB = *(const float4*)&tmp[tid][4];
        int cnt = end - beg;
        float inv = (cnt > 0) ? (1.0f / (float)cnt) : 0.f;
        aA.x = (aA.x + oA.x) * inv; aA.y = (aA.y + oA.y) * inv;
        aA.z = (aA.z + oA.z) * inv; aA.w = (aA.w + oA.w) * inv;
        aB.x = (aB.x + oB.x) * inv; aB.y = (aB.y + oB.y) * inv;
        aB.z = (aB.z + oB.z) * inv; aB.w = (aB.w + oB.w) * inv;
        *(float4*)&mean[node * D + fl] = aA;
        *(float4*)&mean[node * D + fl + 4] = aB;
    }
}

// ---------------- fused SAGE linear: out = relu(A1@W1 + A2@W2 + b) ----------------
#define APAD 132
__global__ __launch_bounds__(256) void sage_linear_kernel(
        const float* __restrict__ A1, const float* __restrict__ A2,
        const float* __restrict__ W1, const float* __restrict__ W2,
        const float* __restrict__ bias, float* __restrict__ out,
        ushort_t* __restrict__ out16, int M) {
    __shared__ float As1[32][APAD];
    __shared__ float As2[32][APAD];
    __shared__ float Ws1[32][D];
    __shared__ float Ws2[32][D];
    int tid = threadIdx.x;
    int r0g = blockIdx.x * 32;
    int ty = tid >> 4;
    int tx = tid & 15;
    int c0 = tx * 8;
    int rl0 = ty, rl1 = ty + 16;

    {
        int row = tid >> 3;
        int rg = r0g + row;
        bool ok = rg < M;
#pragma unroll
        for (int q = 0; q < 4; ++q) {
            int col = ((tid & 7) + q * 8) * 4;
            float4 a1 = make_float4(0.f, 0.f, 0.f, 0.f);
            float4 a2 = make_float4(0.f, 0.f, 0.f, 0.f);
            if (ok) {
                a1 = *(const float4*)&A1[rg * D + col];
                a2 = *(const float4*)&A2[rg * D + col];
            }
            *(float4*)&As1[row][col] = a1;
            *(float4*)&As2[row][col] = a2;
        }
    }

    float4 b_lo = *(const float4*)&bias[c0];
    float4 b_hi = *(const float4*)&bias[c0 + 4];

    float4 acc0l = make_float4(0.f, 0.f, 0.f, 0.f);
    float4 acc0h = make_float4(0.f, 0.f, 0.f, 0.f);
    float4 acc1l = make_float4(0.f, 0.f, 0.f, 0.f);
    float4 acc1h = make_float4(0.f, 0.f, 0.f, 0.f);

    for (int kc = 0; kc < 4; ++kc) {
        __syncthreads();
        {
            int wrow = tid >> 3;
            int grow = kc * 32 + wrow;
#pragma unroll
            for (int q = 0; q < 4; ++q) {
                int col = ((tid & 7) + q * 8) * 4;
                float4 w1 = *(const float4*)&W1[grow * D + col];
                float4 w2 = *(const float4*)&W2[grow * D + col];
                *(float4*)&Ws1[wrow][col] = w1;
                *(float4*)&Ws2[wrow][col] = w2;
            }
        }
        __syncthreads();

#pragma unroll 4
        for (int kk = 0; kk < 32; ++kk) {
            int k = kc * 32 + kk;
            float a10 = As1[rl0][k];
            float a11 = As1[rl1][k];
            float a20 = As2[rl0][k];
            float a21 = As2[rl1][k];
            float4 w1l = *(const float4*)&Ws1[kk][c0];
            float4 w1h = *(const float4*)&Ws1[kk][c0 + 4];
            float4 w2l = *(const float4*)&Ws2[kk][c0];
            float4 w2h = *(const float4*)&Ws2[kk][c0 + 4];
            acc0l.x += a10 * w1l.x + a20 * w2l.x;
            acc0l.y += a10 * w1l.y + a20 * w2l.y;
            acc0l.z += a10 * w1l.z + a20 * w2l.z;
            acc0l.w += a10 * w1l.w + a20 * w2l.w;
            acc0h.x += a10 * w1h.x + a20 * w2h.x;
            acc0h.y += a10 * w1h.y + a20 * w2h.y;
            acc0h.z += a10 * w1h.z + a20 * w2h.z;
            acc0h.w += a10 * w1h.w + a20 * w2h.w;
            acc1l.x += a11 * w1l.x + a21 * w2l.x;
            acc1l.y += a11 * w1l.y + a21 * w2l.y;
            acc1l.z += a11 * w1l.z + a21 * w2l.z;
            acc1l.w += a11 * w1l.w + a21 * w2l.w;
            acc1h.x += a11 * w1h.x + a21 * w2h.x;
            acc1h.y += a11 * w1h.y + a21 * w2h.y;
            acc1h.z += a11 * w1h.z + a21 * w2h.z;
            acc1h.w += a11 * w1h.w + a21 * w2h.w;
        }
    }

    int rg0 = r0g + rl0;
    if (rg0 < M) {
        float4 vl, vh;
        vl.x = fmaxf(acc0l.x + b_lo.x, 0.f); vl.y = fmaxf(acc0l.y + b_lo.y, 0.f);
        vl.z = fmaxf(acc0l.z + b_lo.z, 0.f); vl.w = fmaxf(acc0l.w + b_lo.w, 0.f);
        vh.x = fmaxf(acc0h.x + b_hi.x, 0.f); vh.y = fmaxf(acc0h.y + b_hi.y, 0.f);
        vh.z = fmaxf(acc0h.z + b_hi.z, 0.f); vh.w = fmaxf(acc0h.w + b_hi.w, 0.f);
        *(float4*)&out[rg0 * D + c0] = vl;
        *(float4*)&out[rg0 * D + c0 + 4] = vh;
        if (out16) {
            uint4 o;
            o.x = pack_bf2(vl.x, vl.y); o.y = pack_bf2(vl.z, vl.w);
            o.z = pack_bf2(vh.x, vh.y); o.w = pack_bf2(vh.z, vh.w);
            *(uint4*)&out16[rg0 * D + c0] = o;
        }
    }
    int rg1 = r0g + rl1;
    if (rg1 < M) {
        float4 vl, vh;
        vl.x = fmaxf(acc1l.x + b_lo.x, 0.f); vl.y = fmaxf(acc1l.y + b_lo.y, 0.f);
        vl.z = fmaxf(acc1l.z + b_lo.z, 0.f); vl.w = fmaxf(acc1l.w + b_lo.w, 0.f);
        vh.x = fmaxf(acc1h.x + b_hi.x, 0.f); vh.y = fmaxf(acc1h.y + b_hi.y, 0.f);
        vh.z = fmaxf(acc1h.z + b_hi.z, 0.f); vh.w = fmaxf(acc1h.w + b_hi.w, 0.f);
        *(float4*)&out[rg1 * D + c0] = vl;
        *(float4*)&out[rg1 * D + c0 + 4] = vh;
        if (out16) {
            uint4 o;
            o.x = pack_bf2(vl.x, vl.y); o.y = pack_bf2(vl.z, vl.w);
            o.z = pack_bf2(vh.x, vh.y); o.w = pack_bf2(vh.z, vh.w);
            *(uint4*)&out16[rg1 * D + c0] = o;
        }
    }
}

// ---------------- classifier: sigmoid(h @ Wc + bc) ----------------
__global__ void classifier_kernel(const float* __restrict__ h, const float* __restrict__ Wc,
                                  const float* __restrict__ bc, float* __restrict__ out, int M) {
    int node = blockIdx.x * 4 + ((int)threadIdx.x >> 6);
    int lane = (int)threadIdx.x & 63;
    if (node >= M) return;
    float v = h[node * D + lane] * Wc[lane] + h[node * D + 64 + lane] * Wc[64 + lane];
#pragma unroll
    for (int off = 32; off > 0; off >>= 1) v += __shfl_down(v, off, 64);
    if (lane == 0) {
        float z = v + bc[0];
        out[node] = 1.0f / (1.0f + expf(-z));
    }
}

extern "C" void kernel_launch(void* const* d_in, const int* in_sizes, int n_in,
                              void* d_out, int out_size, void* d_ws, size_t ws_size,
                              hipStream_t stream) {
    const float* x   = (const float*)d_in[0];
    const int* eidx  = (const int*)d_in[1];
    int E = in_sizes[1] / 2;
    const int* src = eidx;
    const int* dst = eidx + E;
    const float* W1l = (const float*)d_in[2];
    const float* b1  = (const float*)d_in[3];
    const float* W1r = (const float*)d_in[4];
    const float* W2l = (const float*)d_in[5];
    const float* b2  = (const float*)d_in[6];
    const float* W2r = (const float*)d_in[7];
    const float* W3l = (const float*)d_in[8];
    const float* b3  = (const float*)d_in[9];
    const float* W3r = (const float*)d_in[10];
    const float* Wc  = (const float*)d_in[11];
    const float* bc  = (const float*)d_in[12];
    float* out = (float*)d_out;

    // workspace carve-up
    char* p = (char*)d_ws;
    int* deg8     = (int*)p;  p += (size_t)NCOPY * N_NODES * 4;   // 320000 (16-mult)
    int* base8    = (int*)p;  p += (size_t)NCOPY * N_NODES * 4;   // 320000
    int* offsets  = (int*)p;  p += 40960;
    int* csr_src  = (int*)p;  p += (size_t)E * 4;
    float* mean   = (float*)p; p += (size_t)N_NODES * D * 4;
    int* pos      = (int*)mean;   // pos is dead before mean is first written
    float* hA     = (float*)p; p += (size_t)N_NODES * D * 4;
    float* hB     = (float*)p; p += (size_t)N_NODES * D * 4;
    ushort_t* h16 = (ushort_t*)p; p += (size_t)N_NODES * D * 2;

    // zero deg8
    int zn16 = (NCOPY * N_NODES * 4) / 16;
    zero_kernel<<<(zn16 + 255) / 256, 256, 0, stream>>>((uint4*)deg8, zn16);

    // bf16 mirror of x (independent of CSR build)
    int n8 = N_NODES * D / 8;
    f2bf_kernel<<<(n8 + 255) / 256, 256, 0, stream>>>(x, h16, n8);

    int eb = (E + 255) / 256;
    rank_kernel<<<eb, 256, 0, stream>>>(dst, E, deg8, pos);
    scan_kernel<<<1, 1024, 0, stream>>>(deg8, offsets, base8, N_NODES);
    csr_write_kernel<<<eb, 256, 0, stream>>>(src, dst, pos, E, base8, csr_src);

    int lin_grid = (N_NODES + 31) / 32;

    // layer 1: gather x16 -> mean; (mean, x) -> hA (+h16)
    aggregate_kernel<<<N_NODES, 128, 0, stream>>>(h16, offsets, csr_src, mean);
    sage_linear_kernel<<<lin_grid, 256, 0, stream>>>(mean, x, W1l, W1r, b1, hA, h16, N_NODES);
    // layer 2
    aggregate_kernel<<<N_NODES, 128, 0, stream>>>(h16, offsets, csr_src, mean);
    sage_linear_kernel<<<lin_grid, 256, 0, stream>>>(mean, hA, W2l, W2r, b2, hB, h16, N_NODES);
    // layer 3 (no bf16 mirror needed)
    aggregate_kernel<<<N_NODES, 128, 0, stream>>>(h16, offsets, csr_src, mean);
    sage_linear_kernel<<<lin_grid, 256, 0, stream>>>(mean, hB, W3l, W3r, b3, hA, (ushort_t*)nullptr, N_NODES);

    // classifier
    classifier_kernel<<<(N_NODES + 3) / 4, 256, 0, stream>>>(hA, Wc, bc, out, N_NODES);
}

// Round 6
// 201.547 us; speedup vs baseline: 1.2556x; 1.2556x over previous
//
#include <hip/hip_runtime.h>
#include <hip/hip_bf16.h>
#include <math.h>

#define N_NODES 10000
#define D 128
#define NCOPY 8

typedef unsigned int uint_t;
typedef unsigned short ushort_t;

// float -> bf16 bits, round-nearest-even (finite inputs only)
__device__ inline uint_t f2bf_bits(float f) {
    uint_t u = __float_as_uint(f);
    return (u + 0x7fffu + ((u >> 16) & 1u)) >> 16;
}
__device__ inline uint_t pack_bf2(float lo, float hi) {
    return (f2bf_bits(hi) << 16) | f2bf_bits(lo);
}

// ---------------- tiny zero fill ----------------
__global__ void zero_kernel(uint4* __restrict__ p, int n16) {
    int i = blockIdx.x * blockDim.x + threadIdx.x;
    if (i < n16) p[i] = make_uint4(0u, 0u, 0u, 0u);
}

// ---------------- CSR build ----------------
// pass 1: 8-way replicated histogram + per-edge rank within copy
__global__ void rank_kernel(const int* __restrict__ dst, int E,
                            int* __restrict__ deg8, int* __restrict__ pos) {
    int i = blockIdx.x * blockDim.x + threadIdx.x;
    if (i < E) {
        int c = blockIdx.x & (NCOPY - 1);
        pos[i] = atomicAdd(&deg8[c * N_NODES + dst[i]], 1);
    }
}

// parallel: tot[i] = sum_c deg8[c][i]
__global__ void sumdeg_kernel(const int* __restrict__ deg8, int* __restrict__ tot, int n) {
    int i = blockIdx.x * blockDim.x + threadIdx.x;
    if (i < n) {
        int s = 0;
#pragma unroll
        for (int c = 0; c < NCOPY; ++c) s += deg8[c * N_NODES + i];
        tot[i] = s;
    }
}

// single-block scan: tot[0..n) -> offsets[0..n]
#define SCAN_PER 10
__global__ __launch_bounds__(1024) void scan_kernel(const int* __restrict__ tot,
                                                    int* __restrict__ offsets, int n) {
    __shared__ int wsum[16];
    __shared__ int wpre[16];
    int tid = threadIdx.x;
    int lane = tid & 63, wid = tid >> 6;
    int base = tid * SCAN_PER;
    int loc[SCAN_PER];
    int s = 0;
#pragma unroll
    for (int q = 0; q < SCAN_PER; ++q) {
        int idx = base + q;
        int v = (idx < n) ? tot[idx] : 0;
        s += v;
        loc[q] = s;
    }
    int mysum = s;
#pragma unroll
    for (int off = 1; off < 64; off <<= 1) {
        int t = __shfl_up(s, off, 64);
        if (lane >= off) s += t;
    }
    if (lane == 63) wsum[wid] = s;
    __syncthreads();
    if (wid == 0 && lane < 16) {
        int v = wsum[lane];
        int ss = v;
#pragma unroll
        for (int off = 1; off < 16; off <<= 1) {
            int t = __shfl_up(ss, off, 16);
            if ((lane & 15) >= off) ss += t;
        }
        wpre[lane] = ss - v;
    }
    __syncthreads();
    int thread_excl = wpre[wid] + (s - mysum);
#pragma unroll
    for (int q = 0; q < SCAN_PER; ++q) {
        int idx = base + q;
        if (idx < n) offsets[idx + 1] = thread_excl + loc[q];
    }
    if (tid == 0) offsets[0] = 0;
}

// parallel: per-copy bases via running prefix within each node
__global__ void base8_kernel(const int* __restrict__ deg8, const int* __restrict__ offsets,
                             int* __restrict__ base8, int n) {
    int i = blockIdx.x * blockDim.x + threadIdx.x;
    if (i < n) {
        int run = offsets[i];
#pragma unroll
        for (int c = 0; c < NCOPY; ++c) {
            base8[c * N_NODES + i] = run;
            run += deg8[c * N_NODES + i];
        }
    }
}

// pass 2: pure streaming write, no atomics
__global__ void csr_write_kernel(const int* __restrict__ src, const int* __restrict__ dst,
                                 const int* __restrict__ pos, int E,
                                 const int* __restrict__ base8, int* __restrict__ csr_src) {
    int i = blockIdx.x * blockDim.x + threadIdx.x;
    if (i < E) {
        int c = (i >> 8) & (NCOPY - 1);  // same copy mapping as rank_kernel (256 thr/block)
        csr_src[base8[c * N_NODES + dst[i]] + pos[i]] = src[i];
    }
}

// ---------------- fp32 -> bf16 mirror ----------------
__global__ void f2bf_kernel(const float* __restrict__ in, ushort_t* __restrict__ out, int n8) {
    int i = blockIdx.x * blockDim.x + threadIdx.x;
    if (i >= n8) return;
    const float4* p = (const float4*)in + (size_t)i * 2;
    float4 a = p[0], b = p[1];
    uint4 o;
    o.x = pack_bf2(a.x, a.y);
    o.y = pack_bf2(a.z, a.w);
    o.z = pack_bf2(b.x, b.y);
    o.w = pack_bf2(b.z, b.w);
    ((uint4*)out)[i] = o;
}

// ---------------- aggregation (segment mean, bf16 gather) ----------------
// 128 threads per node: 8 edge-groups x 16 lanes; each lane covers 8 features (16B)
__global__ __launch_bounds__(128) void aggregate_kernel(const ushort_t* __restrict__ h16,
                                                        const int* __restrict__ offsets,
                                                        const int* __restrict__ csr_src,
                                                        float* __restrict__ mean) {
    __shared__ float tmp[16][8];
    int node = blockIdx.x;
    int tid = threadIdx.x;
    int g = tid >> 4;          // 0..7
    int fl = (tid & 15) * 8;   // feature base
    int beg = offsets[node], end = offsets[node + 1];
    float4 aA = make_float4(0.f, 0.f, 0.f, 0.f);
    float4 aB = make_float4(0.f, 0.f, 0.f, 0.f);
    for (int e = beg + g; e < end; e += 8) {
        int s = csr_src[e];
        uint4 v = *(const uint4*)&h16[s * D + fl];
        aA.x += __uint_as_float(v.x << 16);
        aA.y += __uint_as_float(v.x & 0xffff0000u);
        aA.z += __uint_as_float(v.y << 16);
        aA.w += __uint_as_float(v.y & 0xffff0000u);
        aB.x += __uint_as_float(v.z << 16);
        aB.y += __uint_as_float(v.z & 0xffff0000u);
        aB.z += __uint_as_float(v.w << 16);
        aB.w += __uint_as_float(v.w & 0xffff0000u);
    }
#pragma unroll
    for (int off = 16; off <= 32; off <<= 1) {
        aA.x += __shfl_xor(aA.x, off, 64);
        aA.y += __shfl_xor(aA.y, off, 64);
        aA.z += __shfl_xor(aA.z, off, 64);
        aA.w += __shfl_xor(aA.w, off, 64);
        aB.x += __shfl_xor(aB.x, off, 64);
        aB.y += __shfl_xor(aB.y, off, 64);
        aB.z += __shfl_xor(aB.z, off, 64);
        aB.w += __shfl_xor(aB.w, off, 64);
    }
    if (tid >= 64 && (tid & 63) < 16) {
        int l = tid & 15;
        *(float4*)&tmp[l][0] = aA;
        *(float4*)&tmp[l][4] = aB;
    }
    __syncthreads();
    if (tid < 16) {
        float4 oA = *(const float4*)&tmp[tid][0];
        float4 oB = *(const float4*)&tmp[tid][4];
        int cnt = end - beg;
        float inv = (cnt > 0) ? (1.0f / (float)cnt) : 0.f;
        aA.x = (aA.x + oA.x) * inv; aA.y = (aA.y + oA.y) * inv;
        aA.z = (aA.z + oA.z) * inv; aA.w = (aA.w + oA.w) * inv;
        aB.x = (aB.x + oB.x) * inv; aB.y = (aB.y + oB.y) * inv;
        aB.z = (aB.z + oB.z) * inv; aB.w = (aB.w + oB.w) * inv;
        *(float4*)&mean[node * D + fl] = aA;
        *(float4*)&mean[node * D + fl + 4] = aB;
    }
}

// ---------------- fused SAGE linear: out = relu(A1@W1 + A2@W2 + b) ----------------
#define APAD 132
__global__ __launch_bounds__(256) void sage_linear_kernel(
        const float* __restrict__ A1, const float* __restrict__ A2,
        const float* __restrict__ W1, const float* __restrict__ W2,
        const float* __restrict__ bias, float* __restrict__ out,
        ushort_t* __restrict__ out16, int M) {
    __shared__ float As1[32][APAD];
    __shared__ float As2[32][APAD];
    __shared__ float Ws1[32][D];
    __shared__ float Ws2[32][D];
    int tid = threadIdx.x;
    int r0g = blockIdx.x * 32;
    int ty = tid >> 4;
    int tx = tid & 15;
    int c0 = tx * 8;
    int rl0 = ty, rl1 = ty + 16;

    {
        int row = tid >> 3;
        int rg = r0g + row;
        bool ok = rg < M;
#pragma unroll
        for (int q = 0; q < 4; ++q) {
            int col = ((tid & 7) + q * 8) * 4;
            float4 a1 = make_float4(0.f, 0.f, 0.f, 0.f);
            float4 a2 = make_float4(0.f, 0.f, 0.f, 0.f);
            if (ok) {
                a1 = *(const float4*)&A1[rg * D + col];
                a2 = *(const float4*)&A2[rg * D + col];
            }
            *(float4*)&As1[row][col] = a1;
            *(float4*)&As2[row][col] = a2;
        }
    }

    float4 b_lo = *(const float4*)&bias[c0];
    float4 b_hi = *(const float4*)&bias[c0 + 4];

    float4 acc0l = make_float4(0.f, 0.f, 0.f, 0.f);
    float4 acc0h = make_float4(0.f, 0.f, 0.f, 0.f);
    float4 acc1l = make_float4(0.f, 0.f, 0.f, 0.f);
    float4 acc1h = make_float4(0.f, 0.f, 0.f, 0.f);

    for (int kc = 0; kc < 4; ++kc) {
        __syncthreads();
        {
            int wrow = tid >> 3;
            int grow = kc * 32 + wrow;
#pragma unroll
            for (int q = 0; q < 4; ++q) {
                int col = ((tid & 7) + q * 8) * 4;
                float4 w1 = *(const float4*)&W1[grow * D + col];
                float4 w2 = *(const float4*)&W2[grow * D + col];
                *(float4*)&Ws1[wrow][col] = w1;
                *(float4*)&Ws2[wrow][col] = w2;
            }
        }
        __syncthreads();

#pragma unroll 4
        for (int kk = 0; kk < 32; ++kk) {
            int k = kc * 32 + kk;
            float a10 = As1[rl0][k];
            float a11 = As1[rl1][k];
            float a20 = As2[rl0][k];
            float a21 = As2[rl1][k];
            float4 w1l = *(const float4*)&Ws1[kk][c0];
            float4 w1h = *(const float4*)&Ws1[kk][c0 + 4];
            float4 w2l = *(const float4*)&Ws2[kk][c0];
            float4 w2h = *(const float4*)&Ws2[kk][c0 + 4];
            acc0l.x += a10 * w1l.x + a20 * w2l.x;
            acc0l.y += a10 * w1l.y + a20 * w2l.y;
            acc0l.z += a10 * w1l.z + a20 * w2l.z;
            acc0l.w += a10 * w1l.w + a20 * w2l.w;
            acc0h.x += a10 * w1h.x + a20 * w2h.x;
            acc0h.y += a10 * w1h.y + a20 * w2h.y;
            acc0h.z += a10 * w1h.z + a20 * w2h.z;
            acc0h.w += a10 * w1h.w + a20 * w2h.w;
            acc1l.x += a11 * w1l.x + a21 * w2l.x;
            acc1l.y += a11 * w1l.y + a21 * w2l.y;
            acc1l.z += a11 * w1l.z + a21 * w2l.z;
            acc1l.w += a11 * w1l.w + a21 * w2l.w;
            acc1h.x += a11 * w1h.x + a21 * w2h.x;
            acc1h.y += a11 * w1h.y + a21 * w2h.y;
            acc1h.z += a11 * w1h.z + a21 * w2h.z;
            acc1h.w += a11 * w1h.w + a21 * w2h.w;
        }
    }

    int rg0 = r0g + rl0;
    if (rg0 < M) {
        float4 vl, vh;
        vl.x = fmaxf(acc0l.x + b_lo.x, 0.f); vl.y = fmaxf(acc0l.y + b_lo.y, 0.f);
        vl.z = fmaxf(acc0l.z + b_lo.z, 0.f); vl.w = fmaxf(acc0l.w + b_lo.w, 0.f);
        vh.x = fmaxf(acc0h.x + b_hi.x, 0.f); vh.y = fmaxf(acc0h.y + b_hi.y, 0.f);
        vh.z = fmaxf(acc0h.z + b_hi.z, 0.f); vh.w = fmaxf(acc0h.w + b_hi.w, 0.f);
        *(float4*)&out[rg0 * D + c0] = vl;
        *(float4*)&out[rg0 * D + c0 + 4] = vh;
        if (out16) {
            uint4 o;
            o.x = pack_bf2(vl.x, vl.y); o.y = pack_bf2(vl.z, vl.w);
            o.z = pack_bf2(vh.x, vh.y); o.w = pack_bf2(vh.z, vh.w);
            *(uint4*)&out16[rg0 * D + c0] = o;
        }
    }
    int rg1 = r0g + rl1;
    if (rg1 < M) {
        float4 vl, vh;
        vl.x = fmaxf(acc1l.x + b_lo.x, 0.f); vl.y = fmaxf(acc1l.y + b_lo.y, 0.f);
        vl.z = fmaxf(acc1l.z + b_lo.z, 0.f); vl.w = fmaxf(acc1l.w + b_lo.w, 0.f);
        vh.x = fmaxf(acc1h.x + b_hi.x, 0.f); vh.y = fmaxf(acc1h.y + b_hi.y, 0.f);
        vh.z = fmaxf(acc1h.z + b_hi.z, 0.f); vh.w = fmaxf(acc1h.w + b_hi.w, 0.f);
        *(float4*)&out[rg1 * D + c0] = vl;
        *(float4*)&out[rg1 * D + c0 + 4] = vh;
        if (out16) {
            uint4 o;
            o.x = pack_bf2(vl.x, vl.y); o.y = pack_bf2(vl.z, vl.w);
            o.z = pack_bf2(vh.x, vh.y); o.w = pack_bf2(vh.z, vh.w);
            *(uint4*)&out16[rg1 * D + c0] = o;
        }
    }
}

// ---------------- classifier: sigmoid(h @ Wc + bc) ----------------
__global__ void classifier_kernel(const float* __restrict__ h, const float* __restrict__ Wc,
                                  const float* __restrict__ bc, float* __restrict__ out, int M) {
    int node = blockIdx.x * 4 + ((int)threadIdx.x >> 6);
    int lane = (int)threadIdx.x & 63;
    if (node >= M) return;
    float v = h[node * D + lane] * Wc[lane] + h[node * D + 64 + lane] * Wc[64 + lane];
#pragma unroll
    for (int off = 32; off > 0; off >>= 1) v += __shfl_down(v, off, 64);
    if (lane == 0) {
        float z = v + bc[0];
        out[node] = 1.0f / (1.0f + expf(-z));
    }
}

extern "C" void kernel_launch(void* const* d_in, const int* in_sizes, int n_in,
                              void* d_out, int out_size, void* d_ws, size_t ws_size,
                              hipStream_t stream) {
    const float* x   = (const float*)d_in[0];
    const int* eidx  = (const int*)d_in[1];
    int E = in_sizes[1] / 2;
    const int* src = eidx;
    const int* dst = eidx + E;
    const float* W1l = (const float*)d_in[2];
    const float* b1  = (const float*)d_in[3];
    const float* W1r = (const float*)d_in[4];
    const float* W2l = (const float*)d_in[5];
    const float* b2  = (const float*)d_in[6];
    const float* W2r = (const float*)d_in[7];
    const float* W3l = (const float*)d_in[8];
    const float* b3  = (const float*)d_in[9];
    const float* W3r = (const float*)d_in[10];
    const float* Wc  = (const float*)d_in[11];
    const float* bc  = (const float*)d_in[12];
    float* out = (float*)d_out;

    // workspace carve-up
    char* p = (char*)d_ws;
    int* deg8     = (int*)p;  p += (size_t)NCOPY * N_NODES * 4;   // 320000 (16-mult)
    int* base8    = (int*)p;  p += (size_t)NCOPY * N_NODES * 4;
    int* offsets  = (int*)p;  p += 40960;
    int* tot      = (int*)p;  p += 40960;
    int* csr_src  = (int*)p;  p += (size_t)E * 4;
    float* mean   = (float*)p; p += (size_t)N_NODES * D * 4;
    int* pos      = (int*)mean;   // pos is dead before mean is first written
    float* hA     = (float*)p; p += (size_t)N_NODES * D * 4;
    float* hB     = (float*)p; p += (size_t)N_NODES * D * 4;
    ushort_t* h16 = (ushort_t*)p; p += (size_t)N_NODES * D * 2;

    // zero deg8
    int zn16 = (NCOPY * N_NODES * 4) / 16;
    zero_kernel<<<(zn16 + 255) / 256, 256, 0, stream>>>((uint4*)deg8, zn16);

    // bf16 mirror of x (independent of CSR build)
    int n8 = N_NODES * D / 8;
    f2bf_kernel<<<(n8 + 255) / 256, 256, 0, stream>>>(x, h16, n8);

    int eb = (E + 255) / 256;
    int nb = (N_NODES + 255) / 256;
    rank_kernel<<<eb, 256, 0, stream>>>(dst, E, deg8, pos);
    sumdeg_kernel<<<nb, 256, 0, stream>>>(deg8, tot, N_NODES);
    scan_kernel<<<1, 1024, 0, stream>>>(tot, offsets, N_NODES);
    base8_kernel<<<nb, 256, 0, stream>>>(deg8, offsets, base8, N_NODES);
    csr_write_kernel<<<eb, 256, 0, stream>>>(src, dst, pos, E, base8, csr_src);

    int lin_grid = (N_NODES + 31) / 32;

    // layer 1: gather x16 -> mean; (mean, x) -> hA (+h16)
    aggregate_kernel<<<N_NODES, 128, 0, stream>>>(h16, offsets, csr_src, mean);
    sage_linear_kernel<<<lin_grid, 256, 0, stream>>>(mean, x, W1l, W1r, b1, hA, h16, N_NODES);
    // layer 2
    aggregate_kernel<<<N_NODES, 128, 0, stream>>>(h16, offsets, csr_src, mean);
    sage_linear_kernel<<<lin_grid, 256, 0, stream>>>(mean, hA, W2l, W2r, b2, hB, h16, N_NODES);
    // layer 3 (no bf16 mirror needed)
    aggregate_kernel<<<N_NODES, 128, 0, stream>>>(h16, offsets, csr_src, mean);
    sage_linear_kernel<<<lin_grid, 256, 0, stream>>>(mean, hB, W3l, W3r, b3, hA, (ushort_t*)nullptr, N_NODES);

    // classifier
    classifier_kernel<<<(N_NODES + 3) / 4, 256, 0, stream>>>(hA, Wc, bc, out, N_NODES);
}